// Round 12
// baseline (1649.639 us; speedup 1.0000x reference)
//
#include <hip/hip_runtime.h>

typedef unsigned char u8;
typedef unsigned short u16;
typedef unsigned int u32;
using f32x4 = __attribute__((ext_vector_type(4))) float;
using i32x8 = __attribute__((ext_vector_type(8))) int;

#define EPSF 1e-8f

constexpr int C1 = 768;
constexpr int HW = 9216;       // 96*96
constexpr int CJ = 2304;       // joint channels (= bytes/row in fp8)
constexpr int NS = 72;         // col splits (9216/128)
constexpr int NTKF = 18;       // K-tiles of 128 (2304/128)

// async global->LDS DMA, 16B per lane. LDS dest = wave-uniform base + lane*16.
__device__ __forceinline__ void gl_lds16(const u8* g, u8* l) {
    __builtin_amdgcn_global_load_lds(
        (const __attribute__((address_space(1))) void*)g,
        (__attribute__((address_space(3))) void*)l, 16, 0, 0);
}

// e4m3fn -> f32 (no inf; NaN never occurs for our data)
__device__ __forceinline__ float e4m3f(u32 b) {
    u32 s = b >> 7, e = (b >> 3) & 15, m = b & 7;
    float mag = (e == 0) ? (float)m * 0.001953125f               // m * 2^-9
                         : __uint_as_float(((e + 120) << 23) | (m << 20));
    return s ? -mag : mag;
}

// ---------------- transpose + fp32->fp8(e4m3): out[j][c] = in[c][j] ----------------
__global__ void k_transpose8(const float* __restrict__ s0, const float* __restrict__ s1,
                             const float* __restrict__ s2, u8* __restrict__ dst) {
    __shared__ float tile[32][33];
    const int j0 = blockIdx.x * 32;
    const int c0 = blockIdx.y * 32;
    const int tx = threadIdx.x, ty = threadIdx.y;
    const int seg = (c0 >= 1536) ? 2 : (c0 >= 768) ? 1 : 0;   // 768 not pow2: no & trick
    const float* src = (seg == 0) ? s0 : (seg == 1) ? s1 : s2;
    const int cb = c0 - seg * 768;
#pragma unroll
    for (int r = 0; r < 4; ++r) {
        int cc = ty + r * 8;
        tile[cc][tx] = src[(size_t)(cb + cc) * HW + j0 + tx];
    }
    __syncthreads();
    // write 32j x 32c fp8 as 512 u16 stores (2 packed e4m3 per store), 2 iters
#pragma unroll
    for (int r = 0; r < 2; ++r) {
        int idx = r * 256 + ty * 32 + tx;       // 0..511
        int j = idx >> 4, cp = idx & 15;        // c-pair index
        int p = __builtin_amdgcn_cvt_pk_fp8_f32(tile[cp * 2][j], tile[cp * 2 + 1][j], 0, false);
        *(u16*)(dst + (size_t)(j0 + j) * CJ + c0 + cp * 2) = (u16)p;
    }
}

// ---------------- per-column squared sums + 1/(sqrt(s)+eps) for all 6 mats ----------------
__global__ void k_colsq(const float* __restrict__ p0, const float* __restrict__ p1,
                        const float* __restrict__ p2, const float* __restrict__ p3,
                        const float* __restrict__ p4, const float* __restrict__ p5,
                        float* __restrict__ sq, float* __restrict__ inv) {
    const float* src;
    switch (blockIdx.y) {
        case 0: src = p0; break; case 1: src = p1; break; case 2: src = p2; break;
        case 3: src = p3; break; case 4: src = p4; break; default: src = p5; break;
    }
    const int j = blockIdx.x * 256 + threadIdx.x;
    float s = 0.f;
#pragma unroll 8
    for (int c = 0; c < C1; ++c) {
        float v = src[(size_t)c * HW + j];
        s = fmaf(v, v, s);
    }
    sq[blockIdx.y * HW + j] = s;
    inv[blockIdx.y * HW + j] = 1.0f / (sqrtf(s) + EPSF);
}

// ---------------- joint style norm: 1/(sqrt(s1+s3+s5+EPS)+EPS) ----------------
__global__ void k_joint(const float* __restrict__ sq, float* __restrict__ invbnj) {
    const int j = blockIdx.x * 256 + threadIdx.x;
    float s = sq[1 * HW + j] + sq[3 * HW + j] + sq[5 * HW + j];
    invbnj[j] = 1.0f / (sqrtf(s + EPSF) + EPSF);
}

// ---------------- fused GEMM (G = CT^T*ST via MX-fp8 MFMA K=128) + per-row arg best/worst ----
// Round 12: 256(M)x128(N) tile (staged bytes/output 36 -> 27), 8 waves (4Mx2N, 64x64 each),
// single 48KB LDS buffer -> 3 blocks/CU keeps r11's co-residency overlap. Reduction arrays
// ALIAS ldsA (only live after the K-loop; fenced by __syncthreads). Direct-store epilogue.
__global__ __launch_bounds__(512, 6) void k_gemm_arg(
    const u8* __restrict__ CT, const u8* __restrict__ ST,
    const float* __restrict__ invbn,
    float* __restrict__ bestv, int* __restrict__ besti,
    float* __restrict__ worstv, int* __restrict__ worsti) {
    __shared__ __align__(16) u8 lds[49152];      // [A: 32KB][B: 16KB]
    u8* ldsA = lds;
    u8* ldsB = lds + 32768;
    float* s_bv = (float*)lds;                   // [2][256] aliases ldsA (post-K-loop only)
    int*   s_bi = (int*)(lds + 2048);
    float* s_wv = (float*)(lds + 4096);
    int*   s_wi = (int*)(lds + 6144);

    const int tid = threadIdx.x;
    const int l = tid & 63;
    const int w = tid >> 6;          // 0..7
    const int wr = w >> 1;           // 0..3  (M quarter, 64 rows)
    const int wc = w & 1;            // 0..1  (N half, 64 cols)
    const int rowbase = blockIdx.x * 256;
    const int colbase = blockIdx.y * 128;

    // ---- staging: A = 256 rows x 128 B (32 chunks of 1KB), B = 128 rows x 128 B (16 chunks).
    // Wave w: A rows [w*32,+32) (4 chunks), B rows [w*16,+16) (2 chunks).
    // Lane l: row +(l>>3), slot l&7; source slot pre-swizzled: slot ^ (row&7) = (l&7)^(l>>3).
    const int srow8 = l >> 3;
    const int sslot8 = (l & 7) ^ (l >> 3);
    const u8* gA = CT + (size_t)(rowbase + w * 32 + srow8) * CJ + sslot8 * 16;
    const u8* gB = ST + (size_t)(colbase + w * 16 + srow8) * CJ + sslot8 * 16;
    const int ldsAbase = w * 32 * 128;   // wave-uniform
    const int ldsBbase = w * 16 * 128;

    // ---- fragment read geometry: lane l -> row(l&15), k-chunk (l>>4)*32 bytes,
    // as two b128 at swizzled slots (byte offsets s0b, s1b).
    const int frow = l & 15;
    const int r7 = l & 7;
    const int s0b = ((2 * (l >> 4)) ^ r7) * 16;
    const int s1b = ((2 * (l >> 4) + 1) ^ r7) * 16;
    const int aoff = (wr * 64 + frow) * 128;    // + M*16*128
    const int boff = (wc * 64 + frow) * 128;    // + N*16*128

    f32x4 acc[4][4];
    const f32x4 fzero = {0.f, 0.f, 0.f, 0.f};
#pragma unroll
    for (int M = 0; M < 4; ++M)
#pragma unroll
        for (int N = 0; N < 4; ++N) acc[M][N] = fzero;

#define LDF(dst, basep) {                                                     \
        *(uint4*)&(dst) = *(const uint4*)((basep) + s0b);                     \
        *((uint4*)&(dst) + 1) = *(const uint4*)((basep) + s1b); }

#pragma unroll 1
    for (int t = 0; t < NTKF; ++t) {
        __syncthreads();                         // prior tile's LDS reads done
        const size_t ko = (size_t)t * 128;
#pragma unroll
        for (int c = 0; c < 4; ++c)
            gl_lds16(gA + ko + (size_t)c * 8 * CJ, ldsA + ldsAbase + c * 1024);
#pragma unroll
        for (int c = 0; c < 2; ++c)
            gl_lds16(gB + ko + (size_t)c * 8 * CJ, ldsB + ldsBbase + c * 1024);
        __syncthreads();                         // vmcnt(0) drain; other blocks overlap

        i32x8 bfr[4], fA[4];
#pragma unroll
        for (int N = 0; N < 4; ++N) LDF(bfr[N], ldsB + boff + N * 2048);
#pragma unroll
        for (int M = 0; M < 4; ++M) LDF(fA[M], ldsA + aoff + M * 2048);
#pragma unroll
        for (int M = 0; M < 4; ++M)
#pragma unroll
            for (int N = 0; N < 4; ++N)
                acc[M][N] = __builtin_amdgcn_mfma_scale_f32_16x16x128_f8f6f4(
                    fA[M], bfr[N], acc[M][N], 0, 0, 0, 0x7f7f7f7f, 0, 0x7f7f7f7f);
    }
#undef LDF

    // ---- epilogue: score = G * invbn[col]; per-row best/worst (C/D: col=l&15, row=(l>>4)*4+i)
    float ib[4];
#pragma unroll
    for (int N = 0; N < 4; ++N) ib[N] = invbn[colbase + wc * 64 + N * 16 + frow];

    __syncthreads();                             // all K-loop LDS reads done: safe to alias s_*

#pragma unroll
    for (int M = 0; M < 4; ++M) {
#pragma unroll
        for (int i = 0; i < 4; ++i) {
            float bv = -3.4e38f, wv = 3.4e38f; int bi = 0x7fffffff, wi = 0x7fffffff;
#pragma unroll
            for (int N = 0; N < 4; ++N) {
                float sc = acc[M][N][i] * ib[N];
                int ci = colbase + wc * 64 + N * 16 + frow;
                if (sc > bv) { bv = sc; bi = ci; }
                if (sc < wv) { wv = sc; wi = ci; }
            }
#pragma unroll
            for (int d = 1; d < 16; d <<= 1) {   // reduce across 16 col lanes
                float obv = __shfl_xor(bv, d); int obi = __shfl_xor(bi, d);
                if (obv > bv || (obv == bv && obi < bi)) { bv = obv; bi = obi; }
                float owv = __shfl_xor(wv, d); int owi = __shfl_xor(wi, d);
                if (owv < wv || (owv == wv && owi < wi)) { wv = owv; wi = owi; }
            }
            if ((l & 15) == 0) {                 // each (wc,row) written by exactly one wave
                int rl = wr * 64 + M * 16 + (l >> 4) * 4 + i;
                s_bv[wc * 256 + rl] = bv; s_bi[wc * 256 + rl] = bi;
                s_wv[wc * 256 + rl] = wv; s_wi[wc * 256 + rl] = wi;
            }
        }
    }

    __syncthreads();
    if (tid < 256) {
        float bv = s_bv[tid]; int bi = s_bi[tid];
        float wv = s_wv[tid]; int wi = s_wi[tid];
        float b2 = s_bv[256 + tid]; int i2 = s_bi[256 + tid];
        float w2 = s_wv[256 + tid]; int j2 = s_wi[256 + tid];
        if (b2 > bv || (b2 == bv && i2 < bi)) { bv = b2; bi = i2; }
        if (w2 < wv || (w2 == wv && j2 < wi)) { wv = w2; wi = j2; }
        const int sp = blockIdx.y;
        bestv [(size_t)sp * HW + rowbase + tid] = bv;
        besti [(size_t)sp * HW + rowbase + tid] = bi;
        worstv[(size_t)sp * HW + rowbase + tid] = wv;
        worsti[(size_t)sp * HW + rowbase + tid] = wi;
    }
}

// ---------------- final: reduce splits (72), gathered cosines (fp8 rows), loss ----------------
__global__ void k_final(const u8* __restrict__ CT, const u8* __restrict__ ST,
                        const float* __restrict__ inv6,
                        const float* __restrict__ bestv, const int* __restrict__ besti,
                        const float* __restrict__ worstv, const int* __restrict__ worsti,
                        float* __restrict__ out) {
    const int w = threadIdx.x >> 6, l = threadIdx.x & 63;
    const int r = blockIdx.x * 4 + w;

    // lane l covers split l, and split l+64 when l+64 < NS (NS=72 -> l<8)
    float bv = bestv [(size_t)l * HW + r]; int bi = besti [(size_t)l * HW + r];
    float wv = worstv[(size_t)l * HW + r]; int wi = worsti[(size_t)l * HW + r];
    if (l + 64 < NS) {
        float b2 = bestv [(size_t)(l + 64) * HW + r]; int i2 = besti [(size_t)(l + 64) * HW + r];
        float w2 = worstv[(size_t)(l + 64) * HW + r]; int j2 = worsti[(size_t)(l + 64) * HW + r];
        if (b2 > bv || (b2 == bv && i2 < bi)) { bv = b2; bi = i2; }
        if (w2 < wv || (w2 == wv && j2 < wi)) { wv = w2; wi = j2; }
    }
#pragma unroll
    for (int d = 1; d < 64; d <<= 1) {
        float obv = __shfl_xor(bv, d); int obi = __shfl_xor(bi, d);
        if (obv > bv || (obv == bv && obi < bi)) { bv = obv; bi = obi; }
        float owv = __shfl_xor(wv, d); int owi = __shfl_xor(wi, d);
        if (owv < wv || (owv == wv && owi < wi)) { wv = owv; wi = owi; }
    }
    const int zb = bi, zw = wi;

    const u8* ar = CT + (size_t)r * CJ;
    const u8* bb = ST + (size_t)zb * CJ;
    const u8* bw = ST + (size_t)zw * CJ;
    float db[3] = {0.f, 0.f, 0.f}, dw[3] = {0.f, 0.f, 0.f};
#pragma unroll
    for (int it = 0; it < 9; ++it) {
        const int c = it * 256 + l * 4;
        u32 va = *(const u32*)(ar + c);
        u32 vb = *(const u32*)(bb + c);
        u32 vw = *(const u32*)(bw + c);
        const int seg = it / 3;  // 0: feats, 1: depth, 2: edge (768 = 3*256)
#pragma unroll
        for (int q = 0; q < 4; ++q) {
            float a = e4m3f((va >> (8 * q)) & 0xff);
            float b = e4m3f((vb >> (8 * q)) & 0xff);
            float ww = e4m3f((vw >> (8 * q)) & 0xff);
            db[seg] = fmaf(a, b, db[seg]);
            dw[seg] = fmaf(a, ww, dw[seg]);
        }
    }
#pragma unroll
    for (int d = 1; d < 64; d <<= 1) {
#pragma unroll
        for (int s = 0; s < 3; ++s) {
            db[s] += __shfl_xor(db[s], d);
            dw[s] += __shfl_xor(dw[s], d);
        }
    }
    if (l == 0) {
        float c0 = db[0] * inv6[0 * HW + r] * inv6[1 * HW + zb];
        float c1 = db[1] * inv6[2 * HW + r] * inv6[3 * HW + zb];
        float c2 = db[2] * inv6[4 * HW + r] * inv6[5 * HW + zb];
        float d0 = dw[0] * inv6[0 * HW + r] * inv6[1 * HW + zw];
        float d1 = dw[1] * inv6[2 * HW + r] * inv6[3 * HW + zw];
        float d2 = dw[2] * inv6[4 * HW + r] * inv6[5 * HW + zw];
        float contrib = (6.0f - c0 - c1 - c2 + d0 + d1 + d2) * (1.0f / 9216.0f);
        atomicAdd(out, contrib);
    }
}

extern "C" void kernel_launch(void* const* d_in, const int* in_sizes, int n_in,
                              void* d_out, int out_size, void* d_ws, size_t ws_size,
                              hipStream_t stream) {
    const float* x  = (const float*)d_in[0];
    const float* s  = (const float*)d_in[1];
    const float* rd = (const float*)d_in[2];
    const float* sd = (const float*)d_in[3];
    const float* re = (const float*)d_in[4];
    const float* se = (const float*)d_in[5];

    char* ws = (char*)d_ws;
    const size_t SZ8 = (size_t)HW * CJ;              // 21,233,664 B each (fp8)
    u8*    CT8    = (u8*)ws;
    u8*    ST8    = (u8*)(ws + SZ8);
    float* sq6    = (float*)(ws + 2 * SZ8);          // 6*HW floats
    float* inv6   = sq6 + 6 * HW;                    // 6*HW floats
    float* invbnj = inv6 + 6 * HW;                   // HW floats
    float* bestv  = invbnj + HW;                     // NS*HW floats
    int*   besti  = (int*)(bestv + (size_t)NS * HW);
    float* worstv = (float*)(besti + (size_t)NS * HW);
    int*   worsti = (int*)(worstv + (size_t)NS * HW);
    const size_t NEED = 2 * SZ8 + (size_t)(13 + 4 * NS) * HW * 4;
    if (ws_size < NEED) return;  // ws too small: fail loudly (wrong output)

    hipMemsetAsync(d_out, 0, sizeof(float), stream);

    k_transpose8<<<dim3(HW / 32, CJ / 32), dim3(32, 8), 0, stream>>>(x, rd, re, CT8);
    k_transpose8<<<dim3(HW / 32, CJ / 32), dim3(32, 8), 0, stream>>>(s, sd, se, ST8);
    k_colsq<<<dim3(HW / 256, 6), 256, 0, stream>>>(x, s, rd, sd, re, se, sq6, inv6);
    k_joint<<<HW / 256, 256, 0, stream>>>(sq6, invbnj);
    k_gemm_arg<<<dim3(HW / 256, NS), 512, 0, stream>>>(CT8, ST8, invbnj, bestv, besti, worstv, worsti);
    k_final<<<HW / 4, 256, 0, stream>>>(CT8, ST8, inv6, bestv, besti, worstv, worsti, (float*)d_out);
}

// Round 13
// 662.255 us; speedup vs baseline: 2.4909x; 2.4909x over previous
//
#include <hip/hip_runtime.h>

typedef unsigned char u8;
typedef unsigned short u16;
typedef unsigned int u32;
using f32x4 = __attribute__((ext_vector_type(4))) float;
using i32x8 = __attribute__((ext_vector_type(8))) int;

#define EPSF 1e-8f

constexpr int C1 = 768;
constexpr int HW = 9216;       // 96*96
constexpr int CJ = 2304;       // joint channels (= bytes/row in fp8)
constexpr int NS = 72;         // col splits (9216/128)
constexpr int NTKF = 18;       // K-tiles of 128 (2304/128)

// async global->LDS DMA, 16B per lane. LDS dest = wave-uniform base + lane*16.
__device__ __forceinline__ void gl_lds16(const u8* g, u8* l) {
    __builtin_amdgcn_global_load_lds(
        (const __attribute__((address_space(1))) void*)g,
        (__attribute__((address_space(3))) void*)l, 16, 0, 0);
}

// e4m3fn -> f32 (no inf; NaN never occurs for our data)
__device__ __forceinline__ float e4m3f(u32 b) {
    u32 s = b >> 7, e = (b >> 3) & 15, m = b & 7;
    float mag = (e == 0) ? (float)m * 0.001953125f               // m * 2^-9
                         : __uint_as_float(((e + 120) << 23) | (m << 20));
    return s ? -mag : mag;
}

// ---------------- transpose + fp32->fp8(e4m3): out[j][c] = in[c][j] ----------------
__global__ void k_transpose8(const float* __restrict__ s0, const float* __restrict__ s1,
                             const float* __restrict__ s2, u8* __restrict__ dst) {
    __shared__ float tile[32][33];
    const int j0 = blockIdx.x * 32;
    const int c0 = blockIdx.y * 32;
    const int tx = threadIdx.x, ty = threadIdx.y;
    const int seg = (c0 >= 1536) ? 2 : (c0 >= 768) ? 1 : 0;   // 768 not pow2: no & trick
    const float* src = (seg == 0) ? s0 : (seg == 1) ? s1 : s2;
    const int cb = c0 - seg * 768;
#pragma unroll
    for (int r = 0; r < 4; ++r) {
        int cc = ty + r * 8;
        tile[cc][tx] = src[(size_t)(cb + cc) * HW + j0 + tx];
    }
    __syncthreads();
    // write 32j x 32c fp8 as 512 u16 stores (2 packed e4m3 per store), 2 iters
#pragma unroll
    for (int r = 0; r < 2; ++r) {
        int idx = r * 256 + ty * 32 + tx;       // 0..511
        int j = idx >> 4, cp = idx & 15;        // c-pair index
        int p = __builtin_amdgcn_cvt_pk_fp8_f32(tile[cp * 2][j], tile[cp * 2 + 1][j], 0, false);
        *(u16*)(dst + (size_t)(j0 + j) * CJ + c0 + cp * 2) = (u16)p;
    }
}

// ---------------- per-column squared sums + 1/(sqrt(s)+eps) for all 6 mats ----------------
__global__ void k_colsq(const float* __restrict__ p0, const float* __restrict__ p1,
                        const float* __restrict__ p2, const float* __restrict__ p3,
                        const float* __restrict__ p4, const float* __restrict__ p5,
                        float* __restrict__ sq, float* __restrict__ inv) {
    const float* src;
    switch (blockIdx.y) {
        case 0: src = p0; break; case 1: src = p1; break; case 2: src = p2; break;
        case 3: src = p3; break; case 4: src = p4; break; default: src = p5; break;
    }
    const int j = blockIdx.x * 256 + threadIdx.x;
    float s = 0.f;
#pragma unroll 8
    for (int c = 0; c < C1; ++c) {
        float v = src[(size_t)c * HW + j];
        s = fmaf(v, v, s);
    }
    sq[blockIdx.y * HW + j] = s;
    inv[blockIdx.y * HW + j] = 1.0f / (sqrtf(s) + EPSF);
}

// ---------------- joint style norm: 1/(sqrt(s1+s3+s5+EPS)+EPS) ----------------
__global__ void k_joint(const float* __restrict__ sq, float* __restrict__ invbnj) {
    const int j = blockIdx.x * 256 + threadIdx.x;
    float s = sq[1 * HW + j] + sq[3 * HW + j] + sq[5 * HW + j];
    invbnj[j] = 1.0f / (sqrtf(s + EPSF) + EPSF);
}

// ---------------- fused GEMM (G = CT^T*ST via MX-fp8 MFMA K=128) + per-row arg best/worst ----
// Round 13: r12 structure (256Mx128N tile, 27 staged B/out, 48KB LDS, aliased reductions,
// direct-store epilogue) with the register cap FIXED: __launch_bounds__(512, 2).
// r12's (512,6) capped VGPRs below the accumulator -> full spill to scratch (VGPR 40,
// 6.3GB scratch traffic, 5.8% MfmaUtil). Co-residency (3 blocks/CU) comes from the
// 48KB LDS limit, not the register bound.
__global__ __launch_bounds__(512, 2) void k_gemm_arg(
    const u8* __restrict__ CT, const u8* __restrict__ ST,
    const float* __restrict__ invbn,
    float* __restrict__ bestv, int* __restrict__ besti,
    float* __restrict__ worstv, int* __restrict__ worsti) {
    __shared__ __align__(16) u8 lds[49152];      // [A: 32KB][B: 16KB]
    u8* ldsA = lds;
    u8* ldsB = lds + 32768;
    float* s_bv = (float*)lds;                   // [2][256] aliases ldsA (post-K-loop only)
    int*   s_bi = (int*)(lds + 2048);
    float* s_wv = (float*)(lds + 4096);
    int*   s_wi = (int*)(lds + 6144);

    const int tid = threadIdx.x;
    const int l = tid & 63;
    const int w = tid >> 6;          // 0..7
    const int wr = w >> 1;           // 0..3  (M quarter, 64 rows)
    const int wc = w & 1;            // 0..1  (N half, 64 cols)
    const int rowbase = blockIdx.x * 256;
    const int colbase = blockIdx.y * 128;

    // ---- staging: A = 256 rows x 128 B (32 chunks of 1KB), B = 128 rows x 128 B (16 chunks).
    // Wave w: A rows [w*32,+32) (4 chunks), B rows [w*16,+16) (2 chunks).
    // Lane l: row +(l>>3), slot l&7; source slot pre-swizzled: slot ^ (row&7) = (l&7)^(l>>3).
    const int srow8 = l >> 3;
    const int sslot8 = (l & 7) ^ (l >> 3);
    const u8* gA = CT + (size_t)(rowbase + w * 32 + srow8) * CJ + sslot8 * 16;
    const u8* gB = ST + (size_t)(colbase + w * 16 + srow8) * CJ + sslot8 * 16;
    const int ldsAbase = w * 32 * 128;   // wave-uniform
    const int ldsBbase = w * 16 * 128;

    // ---- fragment read geometry: lane l -> row(l&15), k-chunk (l>>4)*32 bytes,
    // as two b128 at swizzled slots (byte offsets s0b, s1b).
    const int frow = l & 15;
    const int r7 = l & 7;
    const int s0b = ((2 * (l >> 4)) ^ r7) * 16;
    const int s1b = ((2 * (l >> 4) + 1) ^ r7) * 16;
    const int aoff = (wr * 64 + frow) * 128;    // + M*16*128
    const int boff = (wc * 64 + frow) * 128;    // + N*16*128

    f32x4 acc[4][4];
    const f32x4 fzero = {0.f, 0.f, 0.f, 0.f};
#pragma unroll
    for (int M = 0; M < 4; ++M)
#pragma unroll
        for (int N = 0; N < 4; ++N) acc[M][N] = fzero;

#define LDF(dst, basep) {                                                     \
        *(uint4*)&(dst) = *(const uint4*)((basep) + s0b);                     \
        *((uint4*)&(dst) + 1) = *(const uint4*)((basep) + s1b); }

#pragma unroll 1
    for (int t = 0; t < NTKF; ++t) {
        __syncthreads();                         // prior tile's LDS reads done
        const size_t ko = (size_t)t * 128;
#pragma unroll
        for (int c = 0; c < 4; ++c)
            gl_lds16(gA + ko + (size_t)c * 8 * CJ, ldsA + ldsAbase + c * 1024);
#pragma unroll
        for (int c = 0; c < 2; ++c)
            gl_lds16(gB + ko + (size_t)c * 8 * CJ, ldsB + ldsBbase + c * 1024);
        __syncthreads();                         // vmcnt(0) drain; other blocks overlap

        i32x8 bfr[4], fA[4];
#pragma unroll
        for (int N = 0; N < 4; ++N) LDF(bfr[N], ldsB + boff + N * 2048);
#pragma unroll
        for (int M = 0; M < 4; ++M) LDF(fA[M], ldsA + aoff + M * 2048);
#pragma unroll
        for (int M = 0; M < 4; ++M)
#pragma unroll
            for (int N = 0; N < 4; ++N)
                acc[M][N] = __builtin_amdgcn_mfma_scale_f32_16x16x128_f8f6f4(
                    fA[M], bfr[N], acc[M][N], 0, 0, 0, 0x7f7f7f7f, 0, 0x7f7f7f7f);
    }
#undef LDF

    // ---- epilogue: score = G * invbn[col]; per-row best/worst (C/D: col=l&15, row=(l>>4)*4+i)
    float ib[4];
#pragma unroll
    for (int N = 0; N < 4; ++N) ib[N] = invbn[colbase + wc * 64 + N * 16 + frow];

    __syncthreads();                             // all K-loop LDS reads done: safe to alias s_*

#pragma unroll
    for (int M = 0; M < 4; ++M) {
#pragma unroll
        for (int i = 0; i < 4; ++i) {
            float bv = -3.4e38f, wv = 3.4e38f; int bi = 0x7fffffff, wi = 0x7fffffff;
#pragma unroll
            for (int N = 0; N < 4; ++N) {
                float sc = acc[M][N][i] * ib[N];
                int ci = colbase + wc * 64 + N * 16 + frow;
                if (sc > bv) { bv = sc; bi = ci; }
                if (sc < wv) { wv = sc; wi = ci; }
            }
#pragma unroll
            for (int d = 1; d < 16; d <<= 1) {   // reduce across 16 col lanes
                float obv = __shfl_xor(bv, d); int obi = __shfl_xor(bi, d);
                if (obv > bv || (obv == bv && obi < bi)) { bv = obv; bi = obi; }
                float owv = __shfl_xor(wv, d); int owi = __shfl_xor(wi, d);
                if (owv < wv || (owv == wv && owi < wi)) { wv = owv; wi = owi; }
            }
            if ((l & 15) == 0) {                 // each (wc,row) written by exactly one wave
                int rl = wr * 64 + M * 16 + (l >> 4) * 4 + i;
                s_bv[wc * 256 + rl] = bv; s_bi[wc * 256 + rl] = bi;
                s_wv[wc * 256 + rl] = wv; s_wi[wc * 256 + rl] = wi;
            }
        }
    }

    __syncthreads();
    if (tid < 256) {
        float bv = s_bv[tid]; int bi = s_bi[tid];
        float wv = s_wv[tid]; int wi = s_wi[tid];
        float b2 = s_bv[256 + tid]; int i2 = s_bi[256 + tid];
        float w2 = s_wv[256 + tid]; int j2 = s_wi[256 + tid];
        if (b2 > bv || (b2 == bv && i2 < bi)) { bv = b2; bi = i2; }
        if (w2 < wv || (w2 == wv && j2 < wi)) { wv = w2; wi = j2; }
        const int sp = blockIdx.y;
        bestv [(size_t)sp * HW + rowbase + tid] = bv;
        besti [(size_t)sp * HW + rowbase + tid] = bi;
        worstv[(size_t)sp * HW + rowbase + tid] = wv;
        worsti[(size_t)sp * HW + rowbase + tid] = wi;
    }
}

// ---------------- final: reduce splits (72), gathered cosines (fp8 rows), loss ----------------
__global__ void k_final(const u8* __restrict__ CT, const u8* __restrict__ ST,
                        const float* __restrict__ inv6,
                        const float* __restrict__ bestv, const int* __restrict__ besti,
                        const float* __restrict__ worstv, const int* __restrict__ worsti,
                        float* __restrict__ out) {
    const int w = threadIdx.x >> 6, l = threadIdx.x & 63;
    const int r = blockIdx.x * 4 + w;

    // lane l covers split l, and split l+64 when l+64 < NS (NS=72 -> l<8)
    float bv = bestv [(size_t)l * HW + r]; int bi = besti [(size_t)l * HW + r];
    float wv = worstv[(size_t)l * HW + r]; int wi = worsti[(size_t)l * HW + r];
    if (l + 64 < NS) {
        float b2 = bestv [(size_t)(l + 64) * HW + r]; int i2 = besti [(size_t)(l + 64) * HW + r];
        float w2 = worstv[(size_t)(l + 64) * HW + r]; int j2 = worsti[(size_t)(l + 64) * HW + r];
        if (b2 > bv || (b2 == bv && i2 < bi)) { bv = b2; bi = i2; }
        if (w2 < wv || (w2 == wv && j2 < wi)) { wv = w2; wi = j2; }
    }
#pragma unroll
    for (int d = 1; d < 64; d <<= 1) {
        float obv = __shfl_xor(bv, d); int obi = __shfl_xor(bi, d);
        if (obv > bv || (obv == bv && obi < bi)) { bv = obv; bi = obi; }
        float owv = __shfl_xor(wv, d); int owi = __shfl_xor(wi, d);
        if (owv < wv || (owv == wv && owi < wi)) { wv = owv; wi = owi; }
    }
    const int zb = bi, zw = wi;

    const u8* ar = CT + (size_t)r * CJ;
    const u8* bb = ST + (size_t)zb * CJ;
    const u8* bw = ST + (size_t)zw * CJ;
    float db[3] = {0.f, 0.f, 0.f}, dw[3] = {0.f, 0.f, 0.f};
#pragma unroll
    for (int it = 0; it < 9; ++it) {
        const int c = it * 256 + l * 4;
        u32 va = *(const u32*)(ar + c);
        u32 vb = *(const u32*)(bb + c);
        u32 vw = *(const u32*)(bw + c);
        const int seg = it / 3;  // 0: feats, 1: depth, 2: edge (768 = 3*256)
#pragma unroll
        for (int q = 0; q < 4; ++q) {
            float a = e4m3f((va >> (8 * q)) & 0xff);
            float b = e4m3f((vb >> (8 * q)) & 0xff);
            float ww = e4m3f((vw >> (8 * q)) & 0xff);
            db[seg] = fmaf(a, b, db[seg]);
            dw[seg] = fmaf(a, ww, dw[seg]);
        }
    }
#pragma unroll
    for (int d = 1; d < 64; d <<= 1) {
#pragma unroll
        for (int s = 0; s < 3; ++s) {
            db[s] += __shfl_xor(db[s], d);
            dw[s] += __shfl_xor(dw[s], d);
        }
    }
    if (l == 0) {
        float c0 = db[0] * inv6[0 * HW + r] * inv6[1 * HW + zb];
        float c1 = db[1] * inv6[2 * HW + r] * inv6[3 * HW + zb];
        float c2 = db[2] * inv6[4 * HW + r] * inv6[5 * HW + zb];
        float d0 = dw[0] * inv6[0 * HW + r] * inv6[1 * HW + zw];
        float d1 = dw[1] * inv6[2 * HW + r] * inv6[3 * HW + zw];
        float d2 = dw[2] * inv6[4 * HW + r] * inv6[5 * HW + zw];
        float contrib = (6.0f - c0 - c1 - c2 + d0 + d1 + d2) * (1.0f / 9216.0f);
        atomicAdd(out, contrib);
    }
}

extern "C" void kernel_launch(void* const* d_in, const int* in_sizes, int n_in,
                              void* d_out, int out_size, void* d_ws, size_t ws_size,
                              hipStream_t stream) {
    const float* x  = (const float*)d_in[0];
    const float* s  = (const float*)d_in[1];
    const float* rd = (const float*)d_in[2];
    const float* sd = (const float*)d_in[3];
    const float* re = (const float*)d_in[4];
    const float* se = (const float*)d_in[5];

    char* ws = (char*)d_ws;
    const size_t SZ8 = (size_t)HW * CJ;              // 21,233,664 B each (fp8)
    u8*    CT8    = (u8*)ws;
    u8*    ST8    = (u8*)(ws + SZ8);
    float* sq6    = (float*)(ws + 2 * SZ8);          // 6*HW floats
    float* inv6   = sq6 + 6 * HW;                    // 6*HW floats
    float* invbnj = inv6 + 6 * HW;                   // HW floats
    float* bestv  = invbnj + HW;                     // NS*HW floats
    int*   besti  = (int*)(bestv + (size_t)NS * HW);
    float* worstv = (float*)(besti + (size_t)NS * HW);
    int*   worsti = (int*)(worstv + (size_t)NS * HW);
    const size_t NEED = 2 * SZ8 + (size_t)(13 + 4 * NS) * HW * 4;
    if (ws_size < NEED) return;  // ws too small: fail loudly (wrong output)

    hipMemsetAsync(d_out, 0, sizeof(float), stream);

    k_transpose8<<<dim3(HW / 32, CJ / 32), dim3(32, 8), 0, stream>>>(x, rd, re, CT8);
    k_transpose8<<<dim3(HW / 32, CJ / 32), dim3(32, 8), 0, stream>>>(s, sd, se, CT8 == ST8 ? ST8 : ST8);
    k_colsq<<<dim3(HW / 256, 6), 256, 0, stream>>>(x, s, rd, sd, re, se, sq6, inv6);
    k_joint<<<HW / 256, 256, 0, stream>>>(sq6, invbnj);
    k_gemm_arg<<<dim3(HW / 256, NS), 512, 0, stream>>>(CT8, ST8, invbnj, bestv, besti, worstv, worsti);
    k_final<<<HW / 4, 256, 0, stream>>>(CT8, ST8, inv6, bestv, besti, worstv, worsti, (float*)d_out);
}

// Round 14
// 474.396 us; speedup vs baseline: 3.4773x; 1.3960x over previous
//
#include <hip/hip_runtime.h>

typedef unsigned char u8;
typedef unsigned short u16;
typedef unsigned int u32;
using f32x4 = __attribute__((ext_vector_type(4))) float;
using i32x8 = __attribute__((ext_vector_type(8))) int;

#define EPSF 1e-8f

constexpr int C1 = 768;
constexpr int HW = 9216;       // 96*96
constexpr int CJ = 2304;       // joint channels (= bytes/row in fp8)
constexpr int NS = 72;         // col splits (9216/128)
constexpr int NTKF = 18;       // K-tiles of 128 (2304/128)

// async global->LDS DMA, 16B per lane. LDS dest = wave-uniform base + lane*16.
__device__ __forceinline__ void gl_lds16(const u8* g, u8* l) {
    __builtin_amdgcn_global_load_lds(
        (const __attribute__((address_space(1))) void*)g,
        (__attribute__((address_space(3))) void*)l, 16, 0, 0);
}

// e4m3fn -> f32 (no inf; NaN never occurs for our data)
__device__ __forceinline__ float e4m3f(u32 b) {
    u32 s = b >> 7, e = (b >> 3) & 15, m = b & 7;
    float mag = (e == 0) ? (float)m * 0.001953125f               // m * 2^-9
                         : __uint_as_float(((e + 120) << 23) | (m << 20));
    return s ? -mag : mag;
}

// ---------------- fused transpose + fp32->fp8 + column sum-of-squares ----------------
// z=0: content {x, rd, re} -> CT8;  z=1: style {s, sd, se} -> ST8.
// 64x64 tile; while loading, each thread accumulates sum(v^2) for its column ->
// LDS reduce -> one atomicAdd per column into sq6[mat]. Kills the colsq re-read.
__global__ void k_transq(const float* __restrict__ x, const float* __restrict__ s,
                         const float* __restrict__ rd, const float* __restrict__ sd,
                         const float* __restrict__ re, const float* __restrict__ se,
                         u8* __restrict__ CT8, u8* __restrict__ ST8,
                         float* __restrict__ sq6) {
    __shared__ float tile[64][65];
    __shared__ float part[8][64];
    const int j0 = blockIdx.x * 64;
    const int c0 = blockIdx.y * 64;
    const int z = blockIdx.z;
    const int tx = threadIdx.x, ty = threadIdx.y;   // (64, 8)
    const int seg = (c0 >= 1536) ? 2 : (c0 >= 768) ? 1 : 0;   // 768%64==0: no straddle
    const float* src = (z == 0) ? (seg == 0 ? x : seg == 1 ? rd : re)
                                : (seg == 0 ? s : seg == 1 ? sd : se);
    u8* dst = (z == 0) ? CT8 : ST8;
    const int cb = c0 - seg * 768;

    float ss = 0.f;
#pragma unroll
    for (int r = 0; r < 8; ++r) {
        int cc = ty + r * 8;
        float v = src[(size_t)(cb + cc) * HW + j0 + tx];
        tile[cc][tx] = v;
        ss = fmaf(v, v, ss);
    }
    part[ty][tx] = ss;
    __syncthreads();
    if (ty == 0) {
        float t = 0.f;
#pragma unroll
        for (int k = 0; k < 8; ++k) t += part[k][tx];
        atomicAdd(&sq6[(size_t)(seg * 2 + z) * HW + j0 + tx], t);
    }
    // transposed fp8 write: thread -> 4 c-pairs (8B contiguous) of one j-row
    const int tid = ty * 64 + tx;
    const int j = (tid * 4) >> 5;
    const int cp0 = (tid * 4) & 31;
    u16 h[4];
#pragma unroll
    for (int q = 0; q < 4; ++q) {
        int cp = cp0 + q;
        h[q] = (u16)__builtin_amdgcn_cvt_pk_fp8_f32(tile[cp * 2][j], tile[cp * 2 + 1][j], 0, false);
    }
    *(uint2*)(dst + (size_t)(j0 + j) * CJ + c0 + cp0 * 2) = *(const uint2*)h;
}

// ---------------- norms: inv6[m][j] = 1/(sqrt(sq)+eps); joint style norm ----------------
__global__ void k_norms(const float* __restrict__ sq6, float* __restrict__ inv6,
                        float* __restrict__ invbnj) {
    const int j = blockIdx.x * 256 + threadIdx.x;
#pragma unroll
    for (int m = 0; m < 6; ++m)
        inv6[(size_t)m * HW + j] = 1.0f / (sqrtf(sq6[(size_t)m * HW + j]) + EPSF);
    float sjoint = sq6[1 * HW + j] + sq6[3 * HW + j] + sq6[5 * HW + j];
    invbnj[j] = 1.0f / (sqrtf(sjoint + EPSF) + EPSF);
}

// ---------------- fused GEMM (G = CT^T*ST via MX-fp8 MFMA K=128) + per-row arg best/worst ----
// r11 structure verbatim (best measured: 300us, 1.3PF): 128x128 tile, 4 waves (2x2,
// 64x64 each), SINGLE 32KB LDS buffer, plain 2-barrier loop, 4 blocks/CU co-residency
// (VGPR 64 <= the m69 cliff, 36KB LDS). r12/r13 taught: tile growth past 64 VGPR or
// 36KB LDS loses co-residency and regresses.
__global__ __launch_bounds__(256, 4) void k_gemm_arg(
    const u8* __restrict__ CT, const u8* __restrict__ ST,
    const float* __restrict__ invbn,
    float* __restrict__ bestv, int* __restrict__ besti,
    float* __restrict__ worstv, int* __restrict__ worsti) {
    __shared__ __align__(16) u8 ldsA[128 * 128];
    __shared__ __align__(16) u8 ldsB[128 * 128];
    __shared__ float s_bv[2][128]; __shared__ int s_bi[2][128];
    __shared__ float s_wv[2][128]; __shared__ int s_wi[2][128];

    const int tid = threadIdx.x;
    const int l = tid & 63;
    const int w = tid >> 6;          // 0..3
    const int wr = w >> 1;           // 0..1  (M half)
    const int wc = w & 1;            // 0..1  (N half)
    const int rowbase = blockIdx.x * 128;
    const int colbase = blockIdx.y * 128;

    if (tid < 128) {
        s_bv[0][tid] = -3.4e38f; s_bv[1][tid] = -3.4e38f;
        s_wv[0][tid] =  3.4e38f; s_wv[1][tid] =  3.4e38f;
        s_bi[0][tid] = 0x7fffffff; s_bi[1][tid] = 0x7fffffff;
        s_wi[0][tid] = 0x7fffffff; s_wi[1][tid] = 0x7fffffff;
    }

    // staging: A,B = 128 rows x 128 B = 16 chunks of 1KB. Wave w: rows [w*32,+32).
    // Lane l: row +(l>>3), slot l&7; source slot pre-swizzled: slot ^ (row&7) = (l&7)^(l>>3).
    const int srow8 = l >> 3;
    const int sslot8 = (l & 7) ^ (l >> 3);
    const u8* gA = CT + (size_t)(rowbase + w * 32 + srow8) * CJ + sslot8 * 16;
    const u8* gB = ST + (size_t)(colbase + w * 32 + srow8) * CJ + sslot8 * 16;
    const int ldsbase = w * 32 * 128;   // wave-uniform

    // fragment read geometry: lane l -> row(l&15), k-chunk (l>>4)*32 bytes,
    // as two b128 at swizzled slots (byte offsets s0b, s1b).
    const int frow = l & 15;
    const int r7 = l & 7;
    const int s0b = ((2 * (l >> 4)) ^ r7) * 16;
    const int s1b = ((2 * (l >> 4) + 1) ^ r7) * 16;
    const int aoff = (wr * 64 + frow) * 128;    // + M*16*128
    const int boff = (wc * 64 + frow) * 128;    // + N*16*128

    f32x4 acc[4][4];
    const f32x4 fzero = {0.f, 0.f, 0.f, 0.f};
#pragma unroll
    for (int M = 0; M < 4; ++M)
#pragma unroll
        for (int N = 0; N < 4; ++N) acc[M][N] = fzero;

#define LDF(dst, basep) {                                                     \
        *(uint4*)&(dst) = *(const uint4*)((basep) + s0b);                     \
        *((uint4*)&(dst) + 1) = *(const uint4*)((basep) + s1b); }

#pragma unroll 1
    for (int t = 0; t < NTKF; ++t) {
        __syncthreads();                         // prior tile's LDS reads done
        const size_t ko = (size_t)t * 128;
#pragma unroll
        for (int c = 0; c < 4; ++c) {
            gl_lds16(gA + ko + (size_t)c * 8 * CJ, ldsA + ldsbase + c * 1024);
            gl_lds16(gB + ko + (size_t)c * 8 * CJ, ldsB + ldsbase + c * 1024);
        }
        __syncthreads();                         // vmcnt(0) drain; other blocks overlap

        i32x8 bfr[4], fA[4];
#pragma unroll
        for (int N = 0; N < 4; ++N) LDF(bfr[N], ldsB + boff + N * 2048);
#pragma unroll
        for (int M = 0; M < 4; ++M) LDF(fA[M], ldsA + aoff + M * 2048);
#pragma unroll
        for (int M = 0; M < 4; ++M)
#pragma unroll
            for (int N = 0; N < 4; ++N)
                acc[M][N] = __builtin_amdgcn_mfma_scale_f32_16x16x128_f8f6f4(
                    fA[M], bfr[N], acc[M][N], 0, 0, 0, 0x7f7f7f7f, 0, 0x7f7f7f7f);
    }
#undef LDF

    // epilogue: score = G * invbn[col]; per-row best/worst (C/D: col=l&15, row=(l>>4)*4+i)
    float ib[4];
#pragma unroll
    for (int N = 0; N < 4; ++N) ib[N] = invbn[colbase + wc * 64 + N * 16 + frow];

#pragma unroll
    for (int M = 0; M < 4; ++M) {
#pragma unroll
        for (int i = 0; i < 4; ++i) {
            float bv = -3.4e38f, wv = 3.4e38f; int bi = 0x7fffffff, wi = 0x7fffffff;
#pragma unroll
            for (int N = 0; N < 4; ++N) {
                float sc = acc[M][N][i] * ib[N];
                int ci = colbase + wc * 64 + N * 16 + frow;
                if (sc > bv) { bv = sc; bi = ci; }
                if (sc < wv) { wv = sc; wi = ci; }
            }
#pragma unroll
            for (int d = 1; d < 16; d <<= 1) {   // reduce across 16 col lanes
                float obv = __shfl_xor(bv, d); int obi = __shfl_xor(bi, d);
                if (obv > bv || (obv == bv && obi < bi)) { bv = obv; bi = obi; }
                float owv = __shfl_xor(wv, d); int owi = __shfl_xor(wi, d);
                if (owv < wv || (owv == wv && owi < wi)) { wv = owv; wi = owi; }
            }
            if ((l & 15) == 0) {
                int rl = wr * 64 + M * 16 + (l >> 4) * 4 + i;
                if (bv > s_bv[wc][rl] || (bv == s_bv[wc][rl] && bi < s_bi[wc][rl])) { s_bv[wc][rl] = bv; s_bi[wc][rl] = bi; }
                if (wv < s_wv[wc][rl] || (wv == s_wv[wc][rl] && wi < s_wi[wc][rl])) { s_wv[wc][rl] = wv; s_wi[wc][rl] = wi; }
            }
        }
    }

    __syncthreads();
    if (tid < 128) {
        float bv = s_bv[0][tid]; int bi = s_bi[0][tid];
        float wv = s_wv[0][tid]; int wi = s_wi[0][tid];
        if (s_bv[1][tid] > bv || (s_bv[1][tid] == bv && s_bi[1][tid] < bi)) { bv = s_bv[1][tid]; bi = s_bi[1][tid]; }
        if (s_wv[1][tid] < wv || (s_wv[1][tid] == wv && s_wi[1][tid] < wi)) { wv = s_wv[1][tid]; wi = s_wi[1][tid]; }
        const int sp = blockIdx.y;
        bestv [(size_t)sp * HW + rowbase + tid] = bv;
        besti [(size_t)sp * HW + rowbase + tid] = bi;
        worstv[(size_t)sp * HW + rowbase + tid] = wv;
        worsti[(size_t)sp * HW + rowbase + tid] = wi;
    }
}

// ---------------- final: reduce splits (72), gathered cosines (fp8 rows), loss ----------------
__global__ void k_final(const u8* __restrict__ CT, const u8* __restrict__ ST,
                        const float* __restrict__ inv6,
                        const float* __restrict__ bestv, const int* __restrict__ besti,
                        const float* __restrict__ worstv, const int* __restrict__ worsti,
                        float* __restrict__ out) {
    const int w = threadIdx.x >> 6, l = threadIdx.x & 63;
    const int r = blockIdx.x * 4 + w;

    // lane l covers split l, and split l+64 when l+64 < NS (NS=72 -> l<8)
    float bv = bestv [(size_t)l * HW + r]; int bi = besti [(size_t)l * HW + r];
    float wv = worstv[(size_t)l * HW + r]; int wi = worsti[(size_t)l * HW + r];
    if (l + 64 < NS) {
        float b2 = bestv [(size_t)(l + 64) * HW + r]; int i2 = besti [(size_t)(l + 64) * HW + r];
        float w2 = worstv[(size_t)(l + 64) * HW + r]; int j2 = worsti[(size_t)(l + 64) * HW + r];
        if (b2 > bv || (b2 == bv && i2 < bi)) { bv = b2; bi = i2; }
        if (w2 < wv || (w2 == wv && j2 < wi)) { wv = w2; wi = j2; }
    }
#pragma unroll
    for (int d = 1; d < 64; d <<= 1) {
        float obv = __shfl_xor(bv, d); int obi = __shfl_xor(bi, d);
        if (obv > bv || (obv == bv && obi < bi)) { bv = obv; bi = obi; }
        float owv = __shfl_xor(wv, d); int owi = __shfl_xor(wi, d);
        if (owv < wv || (owv == wv && owi < wi)) { wv = owv; wi = owi; }
    }
    const int zb = bi, zw = wi;

    const u8* ar = CT + (size_t)r * CJ;
    const u8* bb = ST + (size_t)zb * CJ;
    const u8* bw = ST + (size_t)zw * CJ;
    float db[3] = {0.f, 0.f, 0.f}, dw[3] = {0.f, 0.f, 0.f};
#pragma unroll
    for (int it = 0; it < 9; ++it) {
        const int c = it * 256 + l * 4;
        u32 va = *(const u32*)(ar + c);
        u32 vb = *(const u32*)(bb + c);
        u32 vw = *(const u32*)(bw + c);
        const int seg = it / 3;  // 0: feats, 1: depth, 2: edge (768 = 3*256)
#pragma unroll
        for (int q = 0; q < 4; ++q) {
            float a = e4m3f((va >> (8 * q)) & 0xff);
            float b = e4m3f((vb >> (8 * q)) & 0xff);
            float ww = e4m3f((vw >> (8 * q)) & 0xff);
            db[seg] = fmaf(a, b, db[seg]);
            dw[seg] = fmaf(a, ww, dw[seg]);
        }
    }
#pragma unroll
    for (int d = 1; d < 64; d <<= 1) {
#pragma unroll
        for (int s = 0; s < 3; ++s) {
            db[s] += __shfl_xor(db[s], d);
            dw[s] += __shfl_xor(dw[s], d);
        }
    }
    if (l == 0) {
        float c0 = db[0] * inv6[0 * HW + r] * inv6[1 * HW + zb];
        float c1 = db[1] * inv6[2 * HW + r] * inv6[3 * HW + zb];
        float c2 = db[2] * inv6[4 * HW + r] * inv6[5 * HW + zb];
        float d0 = dw[0] * inv6[0 * HW + r] * inv6[1 * HW + zw];
        float d1 = dw[1] * inv6[2 * HW + r] * inv6[3 * HW + zw];
        float d2 = dw[2] * inv6[4 * HW + r] * inv6[5 * HW + zw];
        float contrib = (6.0f - c0 - c1 - c2 + d0 + d1 + d2) * (1.0f / 9216.0f);
        atomicAdd(out, contrib);
    }
}

extern "C" void kernel_launch(void* const* d_in, const int* in_sizes, int n_in,
                              void* d_out, int out_size, void* d_ws, size_t ws_size,
                              hipStream_t stream) {
    const float* x  = (const float*)d_in[0];
    const float* s  = (const float*)d_in[1];
    const float* rd = (const float*)d_in[2];
    const float* sd = (const float*)d_in[3];
    const float* re = (const float*)d_in[4];
    const float* se = (const float*)d_in[5];

    char* ws = (char*)d_ws;
    const size_t SZ8 = (size_t)HW * CJ;              // 21,233,664 B each (fp8)
    u8*    CT8    = (u8*)ws;
    u8*    ST8    = (u8*)(ws + SZ8);
    float* sq6    = (float*)(ws + 2 * SZ8);          // 6*HW floats
    float* inv6   = sq6 + 6 * HW;                    // 6*HW floats
    float* invbnj = inv6 + 6 * HW;                   // HW floats
    float* bestv  = invbnj + HW;                     // NS*HW floats
    int*   besti  = (int*)(bestv + (size_t)NS * HW);
    float* worstv = (float*)(besti + (size_t)NS * HW);
    int*   worsti = (int*)(worstv + (size_t)NS * HW);
    const size_t NEED = 2 * SZ8 + (size_t)(13 + 4 * NS) * HW * 4;
    if (ws_size < NEED) return;  // ws too small: fail loudly (wrong output)

    hipMemsetAsync(d_out, 0, sizeof(float), stream);
    hipMemsetAsync(sq6, 0, (size_t)6 * HW * 4, stream);   // k_transq accumulates atomically

    k_transq<<<dim3(HW / 64, CJ / 64, 2), dim3(64, 8), 0, stream>>>(
        x, s, rd, sd, re, se, CT8, ST8, sq6);
    k_norms<<<HW / 256, 256, 0, stream>>>(sq6, inv6, invbnj);
    k_gemm_arg<<<dim3(HW / 128, NS), 256, 0, stream>>>(CT8, ST8, invbnj, bestv, besti, worstv, worsti);
    k_final<<<HW / 4, 256, 0, stream>>>(CT8, ST8, inv6, bestv, besti, worstv, worsti, (float*)d_out);
}